// Round 12
// baseline (128.819 us; speedup 1.0000x reference)
//
#include <hip/hip_runtime.h>
#include <hip/hip_bf16.h>
#include <stdint.h>

#define NIMG 8
#define CIN  64
#define HWI  12544      // 112*112
#define COUT 128

typedef short v8s __attribute__((ext_vector_type(8)));   // 8 bf16 (4 VGPRs)
typedef float v4f __attribute__((ext_vector_type(4)));   // 4 fp32 acc

// fake-quant to int grid: round(x*inv) clamped to [lo,hi]
static __device__ __forceinline__ int q8(float x, float inv, float lo, float hi) {
    float t = rintf(x * inv);
    t = fminf(fmaxf(t, lo), hi);
    return (int)t;
}

// funnel shift: bytes of ({hi,lo} >> sh) — compiler emits v_alignbit_b32
static __device__ __forceinline__ uint32_t funnel(uint32_t hi, uint32_t lo, int sh) {
    return (uint32_t)(((((uint64_t)hi) << 32) | (uint64_t)lo) >> sh);
}

// manual signed-byte dot4
static __device__ __forceinline__ int dot4(uint32_t a, uint32_t b, int c) {
    int acc = c;
    #pragma unroll
    for (int i = 0; i < 4; ++i)
        acc += (int)(int8_t)(a >> (8*i)) * (int)(int8_t)(b >> (8*i));
    return acc;
}

// exact int -> bf16 bits (|v| <= 256 fits in 8 significand bits)
static __device__ __forceinline__ uint16_t i2bf(int v) {
    union { float f; uint32_t u; } c; c.f = (float)v;
    return (uint16_t)(c.u >> 16);
}

// ---------------------------------------------------------------------------
// K0: quantize 1x1 weights into bf16 matrix [128 co][128 k] in ws
// ---------------------------------------------------------------------------
__global__ void __launch_bounds__(256) wprep_kernel(
    const float* __restrict__ w2, const float* __restrict__ wsc,
    const float* __restrict__ sw2p, const float* __restrict__ swscp,
    uint16_t* __restrict__ wbuf)
{
    int t = blockIdx.x * 256 + threadIdx.x;   // 2048 threads, 4 weights each
    int f = t * 4;
    int co = f >> 6, k = f & 63;
    float inv2 = 1.0f / sw2p[0];
    float invs = 1.0f / swscp[0];
    float4 a = *(const float4*)(w2 + f);
    float4 b = *(const float4*)(wsc + f);
    float av[4] = {a.x, a.y, a.z, a.w};
    float bv[4] = {b.x, b.y, b.z, b.w};
    uint16_t* d2 = wbuf + co*128 + k;
    uint16_t* ds = wbuf + co*128 + 64 + k;
    *(ushort2*)(d2)     = make_ushort2(i2bf(q8(av[0], inv2, -128.f, 127.f)),
                                       i2bf(q8(av[1], inv2, -128.f, 127.f)));
    *(ushort2*)(d2 + 2) = make_ushort2(i2bf(q8(av[2], inv2, -128.f, 127.f)),
                                       i2bf(q8(av[3], inv2, -128.f, 127.f)));
    *(ushort2*)(ds)     = make_ushort2(i2bf(q8(bv[0], invs, -128.f, 127.f)),
                                       i2bf(q8(bv[1], invs, -128.f, 127.f)));
    *(ushort2*)(ds + 2) = make_ushort2(i2bf(q8(bv[2], invs, -128.f, 127.f)),
                                       i2bf(q8(bv[3], invs, -128.f, 127.f)));
}

// ---------------------------------------------------------------------------
// K1 (fused, 1 row/block, 896 blocks, MLP-maximized):
//   ph0: hoisted loads — w1 taps, A fragments, scalars (overlap ph1 latency)
//   ph1: BATCHED x loads (21 float4 in flight, one wait) -> quant -> tile
//   ph2: depthwise 3x3 int + relu-quant -> Bl bf16 [112 px][136]  (unrolled)
//   ph3: MFMA GEMM, depth-1 LDS prefetch, fp32 out
// LDS = 22272 + 30464 = 52736 B -> 3 blocks/CU; launch_bounds(256,3) -> ~170 VGPR.
// ---------------------------------------------------------------------------
__global__ void __launch_bounds__(256, 3) fused_kernel(
    const float* __restrict__ x, const float* __restrict__ w1,
    const uint16_t* __restrict__ wbuf,
    const float* __restrict__ sinp, const float* __restrict__ srelup,
    const float* __restrict__ saddp, const float* __restrict__ sw1p,
    const float* __restrict__ sw2p, const float* __restrict__ swscp,
    float* __restrict__ out)
{
    __shared__ int8_t   tile[64 * 348];   // c-stride 348 B (87 dwords, odd)
    __shared__ uint16_t Bl[112 * 136];    // px-stride 272 B (16B-aligned for b128)

    int bid = blockIdx.x;
    int n = bid / 112, h = bid - n*112;
    int tid = threadIdx.x;
    int wave = tid >> 6, lane = tid & 63;
    int lr = lane >> 4, ln = lane & 15;
    float sin_f = sinp[0];
    float inv_sin = 1.0f / sin_f;

    // ---- phase 0a: depthwise taps for this thread's channel (9 loads) ----
    int c = lane;
    float isw1 = 1.0f / sw1p[0];
    uint32_t wp[3];
    #pragma unroll
    for (int ky = 0; ky < 3; ++ky) {
        uint32_t pk = 0;
        #pragma unroll
        for (int kx = 0; kx < 3; ++kx) {
            int q = q8(w1[c*9 + ky*3 + kx], isw1, -128.0f, 127.0f);
            pk |= (uint32_t)(q & 255) << (8*kx);
        }
        wp[ky] = pk;
    }

    // ---- phase 0b: A fragments (8 x 16B loads, L2-resident weight matrix) ----
    v8s a[2][4];
    #pragma unroll
    for (int mi = 0; mi < 2; ++mi) {
        int m = (wave*2 + mi)*16 + ln;
        #pragma unroll
        for (int seg = 0; seg < 4; ++seg)
            a[mi][seg] = *(const v8s*)(wbuf + (size_t)m*128 + seg*32 + lr*8);
    }

    // ---- phase 1: BATCHED stage of 3 halo rows x 64 ch x 112 cols ----
    float4 vals[21];
    #pragma unroll
    for (int i = 0; i < 21; ++i) {
        int id = tid + i*256;
        int cc = id / 84; int rem = id - cc*84;
        int r = rem / 28; int seg = rem - r*28;
        int grow = h + r - 1;
        vals[i] = make_float4(0.f, 0.f, 0.f, 0.f);
        if ((unsigned)grow < 112u)
            vals[i] = *(const float4*)(x + ((size_t)(n*64 + cc) * HWI + grow*112 + seg*4));
    }
    #pragma unroll
    for (int i = 0; i < 21; ++i) {
        int id = tid + i*256;
        int cc = id / 84; int rem = id - cc*84;
        int r = rem / 28; int seg = rem - r*28;
        float vv[4] = {vals[i].x, vals[i].y, vals[i].z, vals[i].w};
        uint32_t pk = 0;
        #pragma unroll
        for (int e = 0; e < 4; ++e) {
            int q = q8(vv[e], inv_sin, -128.0f, 127.0f);
            pk |= (uint32_t)(q & 255) << (8*e);
        }
        *(uint32_t*)&tile[cc*348 + r*116 + seg*4] = pk;
    }
    if (tid < 192) {  // zero pad cols 112..115 of each (c, r)
        int cc = tid / 3, r = tid - cc*3;
        *(uint32_t*)&tile[cc*348 + r*116 + 112] = 0;
    }
    __syncthreads();

    // ---- phase 2: depthwise 3x3 + relu-quant; write bf16 yq/xq into Bl ----
    {
        int w0b = wave * 28;              // 28-px quarter of the row
        float r1 = (sin_f * sw1p[0]) / srelup[0];

        int base[3];
        #pragma unroll
        for (int r2 = 0; r2 < 3; ++r2) base[r2] = c*348 + r2*116;

        uint32_t Ar[3], Br[3], Cr[3];
        #pragma unroll
        for (int r2 = 0; r2 < 3; ++r2) {
            Ar[r2] = wave ? *(uint32_t*)&tile[base[r2] + w0b - 4] : 0u;
            Br[r2] = *(uint32_t*)&tile[base[r2] + w0b];
            Cr[r2] = *(uint32_t*)&tile[base[r2] + w0b + 4];
        }

        #pragma unroll
        for (int q = 0; q < 7; ++q) {
            int acc0 = 0, acc1 = 0, acc2 = 0, acc3 = 0;
            #pragma unroll
            for (int r2 = 0; r2 < 3; ++r2) {
                uint32_t d0 = funnel(Br[r2], Ar[r2], 24);
                uint32_t d1 = Br[r2];
                uint32_t d2 = funnel(Cr[r2], Br[r2], 8);
                uint32_t d3 = funnel(Cr[r2], Br[r2], 16);
                acc0 = dot4(d0, wp[r2], acc0);
                acc1 = dot4(d1, wp[r2], acc1);
                acc2 = dot4(d2, wp[r2], acc2);
                acc3 = dot4(d3, wp[r2], acc3);
            }
            int accs[4] = {acc0, acc1, acc2, acc3};
            uint32_t xdw = Br[1];
            int pxb = w0b + q*4;
            #pragma unroll
            for (int j = 0; j < 4; ++j) {
                float t = rintf((float)accs[j] * r1);
                t = fminf(fmaxf(t, 0.0f), 255.0f);
                int xv = (int)(int8_t)((xdw >> (8*j)) & 255);
                Bl[(pxb + j)*136 + c]      = i2bf((int)t);   // yq
                Bl[(pxb + j)*136 + 64 + c] = i2bf(xv);       // xq
            }
            #pragma unroll
            for (int r2 = 0; r2 < 3; ++r2) { Ar[r2] = Br[r2]; Br[r2] = Cr[r2]; }
            if (q < 6) {
                #pragma unroll
                for (int r2 = 0; r2 < 3; ++r2)
                    Cr[r2] = *(uint32_t*)&tile[base[r2] + w0b + q*4 + 8];
            }
        }
    }
    __syncthreads();

    // ---- phase 3: GEMM (mfma_f32_16x16x32_bf16), depth-1 prefetch ----
    {
        float S2  = sw2p[0] * srelup[0];
        float Ssc = swscp[0] * sinp[0];
        float sadd = saddp[0];
        float inv_sadd = 1.0f / sadd;

        size_t orow = (size_t)n*COUT*HWI + (size_t)h*112;

        v8s bf[4];
        {
            int boff = ln*136 + lr*8;
            #pragma unroll
            for (int seg = 0; seg < 4; ++seg)
                bf[seg] = *(const v8s*)&Bl[boff + seg*32];
        }

        for (int nt = 0; nt < 7; ++nt) {
            v8s bfn[4];
            if (nt < 6) {
                int boff = ((nt+1)*16 + ln)*136 + lr*8;
                #pragma unroll
                for (int seg = 0; seg < 4; ++seg)
                    bfn[seg] = *(const v8s*)&Bl[boff + seg*32];
            }
            #pragma unroll
            for (int mi = 0; mi < 2; ++mi) {
                v4f acc2 = {0.f, 0.f, 0.f, 0.f};
                v4f accs = {0.f, 0.f, 0.f, 0.f};
                acc2 = __builtin_amdgcn_mfma_f32_16x16x32_bf16(a[mi][0], bf[0], acc2, 0, 0, 0);
                acc2 = __builtin_amdgcn_mfma_f32_16x16x32_bf16(a[mi][1], bf[1], acc2, 0, 0, 0);
                accs = __builtin_amdgcn_mfma_f32_16x16x32_bf16(a[mi][2], bf[2], accs, 0, 0, 0);
                accs = __builtin_amdgcn_mfma_f32_16x16x32_bf16(a[mi][3], bf[3], accs, 0, 0, 0);
                size_t obase = orow + (size_t)((wave*2 + mi)*16 + lr*4)*HWI + nt*16 + ln;
                #pragma unroll
                for (int r = 0; r < 4; ++r) {
                    float v = S2 * acc2[r] + Ssc * accs[r];
                    float t = rintf(v * inv_sadd);
                    t = fminf(fmaxf(t, -128.0f), 127.0f);
                    out[obase + (size_t)r*HWI] = t * sadd;
                }
            }
            if (nt < 6) {
                #pragma unroll
                for (int seg = 0; seg < 4; ++seg) bf[seg] = bfn[seg];
            }
        }
    }
}

// ---------------------------------------------------------------------------
extern "C" void kernel_launch(void* const* d_in, const int* in_sizes, int n_in,
                              void* d_out, int out_size, void* d_ws, size_t ws_size,
                              hipStream_t stream) {
    const float* x     = (const float*)d_in[0];
    const float* w1    = (const float*)d_in[1];
    const float* w2    = (const float*)d_in[2];
    const float* wsc   = (const float*)d_in[3];
    const float* sin   = (const float*)d_in[4];
    const float* srelu = (const float*)d_in[5];
    const float* sadd  = (const float*)d_in[6];
    const float* sw1   = (const float*)d_in[7];
    const float* sw2   = (const float*)d_in[8];
    const float* swsc  = (const float*)d_in[9];

    uint16_t* wbuf = (uint16_t*)d_ws;   // 32 KB bf16 weight matrix

    wprep_kernel<<<8, 256, 0, stream>>>(w2, wsc, sw2, swsc, wbuf);
    fused_kernel<<<NIMG * 112, 256, 0, stream>>>(x, w1, wbuf,
                                                 sin, srelu, sadd, sw1, sw2, swsc,
                                                 (float*)d_out);
}

// Round 13
// 118.719 us; speedup vs baseline: 1.0851x; 1.0851x over previous
//
#include <hip/hip_runtime.h>
#include <hip/hip_bf16.h>
#include <stdint.h>

#define NIMG 8
#define CIN  64
#define HWI  12544      // 112*112
#define COUT 128

typedef short v8s __attribute__((ext_vector_type(8)));   // 8 bf16 (4 VGPRs)
typedef float v4f __attribute__((ext_vector_type(4)));   // 4 fp32 acc

// fake-quant to int grid: round(x*inv) clamped to [lo,hi]
static __device__ __forceinline__ int q8(float x, float inv, float lo, float hi) {
    float t = rintf(x * inv);
    t = fminf(fmaxf(t, lo), hi);
    return (int)t;
}

// funnel shift: bytes of ({hi,lo} >> sh) — compiler emits v_alignbit_b32
static __device__ __forceinline__ uint32_t funnel(uint32_t hi, uint32_t lo, int sh) {
    return (uint32_t)(((((uint64_t)hi) << 32) | (uint64_t)lo) >> sh);
}

// manual signed-byte dot4
static __device__ __forceinline__ int dot4(uint32_t a, uint32_t b, int c) {
    int acc = c;
    #pragma unroll
    for (int i = 0; i < 4; ++i)
        acc += (int)(int8_t)(a >> (8*i)) * (int)(int8_t)(b >> (8*i));
    return acc;
}

// exact int -> bf16 bits (|v| <= 256 fits in 8 significand bits)
static __device__ __forceinline__ uint16_t i2bf(int v) {
    union { float f; uint32_t u; } c; c.f = (float)v;
    return (uint16_t)(c.u >> 16);
}

// ---------------------------------------------------------------------------
// K0: quantize 1x1 weights into bf16 matrix [128 co][128 k] in ws
// ---------------------------------------------------------------------------
__global__ void __launch_bounds__(256) wprep_kernel(
    const float* __restrict__ w2, const float* __restrict__ wsc,
    const float* __restrict__ sw2p, const float* __restrict__ swscp,
    uint16_t* __restrict__ wbuf)
{
    int t = blockIdx.x * 256 + threadIdx.x;   // 2048 threads, 4 weights each
    int f = t * 4;
    int co = f >> 6, k = f & 63;
    float inv2 = 1.0f / sw2p[0];
    float invs = 1.0f / swscp[0];
    float4 a = *(const float4*)(w2 + f);
    float4 b = *(const float4*)(wsc + f);
    float av[4] = {a.x, a.y, a.z, a.w};
    float bv[4] = {b.x, b.y, b.z, b.w};
    uint16_t* d2 = wbuf + co*128 + k;
    uint16_t* ds = wbuf + co*128 + 64 + k;
    *(ushort2*)(d2)     = make_ushort2(i2bf(q8(av[0], inv2, -128.f, 127.f)),
                                       i2bf(q8(av[1], inv2, -128.f, 127.f)));
    *(ushort2*)(d2 + 2) = make_ushort2(i2bf(q8(av[2], inv2, -128.f, 127.f)),
                                       i2bf(q8(av[3], inv2, -128.f, 127.f)));
    *(ushort2*)(ds)     = make_ushort2(i2bf(q8(bv[0], invs, -128.f, 127.f)),
                                       i2bf(q8(bv[1], invs, -128.f, 127.f)));
    *(ushort2*)(ds + 2) = make_ushort2(i2bf(q8(bv[2], invs, -128.f, 127.f)),
                                       i2bf(q8(bv[3], invs, -128.f, 127.f)));
}

// ---------------------------------------------------------------------------
// K1 (fused, 1 row/block, 896 blocks):
//   ph0: hoisted loads — w1 taps, A fragments (overlap ph1 latency)
//   ph1: x loads in 3 batches of 7 float4 (bounded MLP, no spill) -> tile
//   ph2: depthwise 3x3 int + relu-quant -> Bl int8 [112 px][132]
//   ph3: MFMA GEMM, int8->bf16 unpack (proven cost-neutral), fp32 out
// LDS = 22272 (tile) + 14784 (Bl) = 37056 B -> 4 blocks/CU (148 KB).
// launch_bounds(256,4): VGPR cap 128 = 4 waves/SIMD — matches 4 blocks/CU.
// ---------------------------------------------------------------------------
__global__ void __launch_bounds__(256, 4) fused_kernel(
    const float* __restrict__ x, const float* __restrict__ w1,
    const uint16_t* __restrict__ wbuf,
    const float* __restrict__ sinp, const float* __restrict__ srelup,
    const float* __restrict__ saddp, const float* __restrict__ sw1p,
    const float* __restrict__ sw2p, const float* __restrict__ swscp,
    float* __restrict__ out)
{
    __shared__ int8_t tile[64 * 348];   // c-stride 348 B (87 dwords, odd)
    __shared__ int8_t Bl[112 * 132];    // px-stride 132 B

    int bid = blockIdx.x;
    int n = bid / 112, h = bid - n*112;
    int tid = threadIdx.x;
    int wave = tid >> 6, lane = tid & 63;
    int lr = lane >> 4, ln = lane & 15;
    float sin_f = sinp[0];
    float inv_sin = 1.0f / sin_f;

    // ---- phase 0a: depthwise taps for this thread's channel ----
    int c = lane;
    float isw1 = 1.0f / sw1p[0];
    uint32_t wp[3];
    #pragma unroll
    for (int ky = 0; ky < 3; ++ky) {
        uint32_t pk = 0;
        #pragma unroll
        for (int kx = 0; kx < 3; ++kx) {
            int q = q8(w1[c*9 + ky*3 + kx], isw1, -128.0f, 127.0f);
            pk |= (uint32_t)(q & 255) << (8*kx);
        }
        wp[ky] = pk;
    }

    // ---- phase 0b: A fragments (8 x 16B loads, L2-resident) ----
    v8s a[2][4];
    #pragma unroll
    for (int mi = 0; mi < 2; ++mi) {
        int m = (wave*2 + mi)*16 + ln;
        #pragma unroll
        for (int seg = 0; seg < 4; ++seg)
            a[mi][seg] = *(const v8s*)(wbuf + (size_t)m*128 + seg*32 + lr*8);
    }

    // ---- phase 1: 3 batches of 7 float4 (28 VGPRs in flight) ----
    #pragma unroll
    for (int b = 0; b < 3; ++b) {
        float4 vals[7];
        #pragma unroll
        for (int i = 0; i < 7; ++i) {
            int id = tid + (b*7 + i)*256;
            int cc = id / 84; int rem = id - cc*84;
            int r = rem / 28; int seg = rem - r*28;
            int grow = h + r - 1;
            vals[i] = make_float4(0.f, 0.f, 0.f, 0.f);
            if ((unsigned)grow < 112u)
                vals[i] = *(const float4*)(x + ((size_t)(n*64 + cc) * HWI + grow*112 + seg*4));
        }
        #pragma unroll
        for (int i = 0; i < 7; ++i) {
            int id = tid + (b*7 + i)*256;
            int cc = id / 84; int rem = id - cc*84;
            int r = rem / 28; int seg = rem - r*28;
            float vv[4] = {vals[i].x, vals[i].y, vals[i].z, vals[i].w};
            uint32_t pk = 0;
            #pragma unroll
            for (int e = 0; e < 4; ++e) {
                int q = q8(vv[e], inv_sin, -128.0f, 127.0f);
                pk |= (uint32_t)(q & 255) << (8*e);
            }
            *(uint32_t*)&tile[cc*348 + r*116 + seg*4] = pk;
        }
    }
    if (tid < 192) {  // zero pad cols 112..115 of each (c, r)
        int cc = tid / 3, r = tid - cc*3;
        *(uint32_t*)&tile[cc*348 + r*116 + 112] = 0;
    }
    __syncthreads();

    // ---- phase 2: depthwise 3x3 + relu-quant; write int8 yq/xq into Bl ----
    {
        int w0b = wave * 28;              // 28-px quarter of the row
        float r1 = (sin_f * sw1p[0]) / srelup[0];

        int base[3];
        #pragma unroll
        for (int r2 = 0; r2 < 3; ++r2) base[r2] = c*348 + r2*116;

        uint32_t Ar[3], Br[3], Cr[3];
        #pragma unroll
        for (int r2 = 0; r2 < 3; ++r2) {
            Ar[r2] = wave ? *(uint32_t*)&tile[base[r2] + w0b - 4] : 0u;
            Br[r2] = *(uint32_t*)&tile[base[r2] + w0b];
            Cr[r2] = *(uint32_t*)&tile[base[r2] + w0b + 4];
        }

        #pragma unroll
        for (int q = 0; q < 7; ++q) {
            int acc0 = 0, acc1 = 0, acc2 = 0, acc3 = 0;
            #pragma unroll
            for (int r2 = 0; r2 < 3; ++r2) {
                uint32_t d0 = funnel(Br[r2], Ar[r2], 24);
                uint32_t d1 = Br[r2];
                uint32_t d2 = funnel(Cr[r2], Br[r2], 8);
                uint32_t d3 = funnel(Cr[r2], Br[r2], 16);
                acc0 = dot4(d0, wp[r2], acc0);
                acc1 = dot4(d1, wp[r2], acc1);
                acc2 = dot4(d2, wp[r2], acc2);
                acc3 = dot4(d3, wp[r2], acc3);
            }
            int accs[4] = {acc0, acc1, acc2, acc3};
            uint32_t xdw = Br[1];
            int pxb = w0b + q*4;
            #pragma unroll
            for (int j = 0; j < 4; ++j) {
                float t = rintf((float)accs[j] * r1);
                t = fminf(fmaxf(t, 0.0f), 255.0f);
                Bl[(pxb + j)*132 + c]      = (int8_t)(int)t;                 // yq (uint8 bits)
                Bl[(pxb + j)*132 + 64 + c] = (int8_t)((xdw >> (8*j)) & 255); // xq
            }
            #pragma unroll
            for (int r2 = 0; r2 < 3; ++r2) { Ar[r2] = Br[r2]; Br[r2] = Cr[r2]; }
            if (q < 6) {
                #pragma unroll
                for (int r2 = 0; r2 < 3; ++r2)
                    Cr[r2] = *(uint32_t*)&tile[base[r2] + w0b + q*4 + 8];
            }
        }
    }
    __syncthreads();

    // ---- phase 3: GEMM (mfma_f32_16x16x32_bf16) + requant epilogue ----
    {
        float S2  = sw2p[0] * srelup[0];
        float Ssc = swscp[0] * sinp[0];
        float sadd = saddp[0];
        float inv_sadd = 1.0f / sadd;

        size_t orow = (size_t)n*COUT*HWI + (size_t)h*112;

        for (int nt = 0; nt < 7; ++nt) {
            int boff = (nt*16 + ln)*132 + lr*8;
            v8s bf[4];
            #pragma unroll
            for (int seg = 0; seg < 4; ++seg) {
                uint32_t d0 = *(const uint32_t*)&Bl[boff + seg*32];
                uint32_t d1 = *(const uint32_t*)&Bl[boff + seg*32 + 4];
                v8s t;
                if (seg < 2) {
                    #pragma unroll
                    for (int e = 0; e < 4; ++e) {
                        t[e]     = (short)i2bf((int)((d0 >> (8*e)) & 255u));
                        t[4 + e] = (short)i2bf((int)((d1 >> (8*e)) & 255u));
                    }
                } else {
                    #pragma unroll
                    for (int e = 0; e < 4; ++e) {
                        t[e]     = (short)i2bf((int)(int8_t)(d0 >> (8*e)));
                        t[4 + e] = (short)i2bf((int)(int8_t)(d1 >> (8*e)));
                    }
                }
                bf[seg] = t;
            }
            #pragma unroll
            for (int mi = 0; mi < 2; ++mi) {
                v4f acc2 = {0.f, 0.f, 0.f, 0.f};
                v4f accs = {0.f, 0.f, 0.f, 0.f};
                acc2 = __builtin_amdgcn_mfma_f32_16x16x32_bf16(a[mi][0], bf[0], acc2, 0, 0, 0);
                acc2 = __builtin_amdgcn_mfma_f32_16x16x32_bf16(a[mi][1], bf[1], acc2, 0, 0, 0);
                accs = __builtin_amdgcn_mfma_f32_16x16x32_bf16(a[mi][2], bf[2], accs, 0, 0, 0);
                accs = __builtin_amdgcn_mfma_f32_16x16x32_bf16(a[mi][3], bf[3], accs, 0, 0, 0);
                size_t obase = orow + (size_t)((wave*2 + mi)*16 + lr*4)*HWI + nt*16 + ln;
                #pragma unroll
                for (int r = 0; r < 4; ++r) {
                    float v = S2 * acc2[r] + Ssc * accs[r];
                    float t = rintf(v * inv_sadd);
                    t = fminf(fmaxf(t, -128.0f), 127.0f);
                    out[obase + (size_t)r*HWI] = t * sadd;
                }
            }
        }
    }
}

// ---------------------------------------------------------------------------
extern "C" void kernel_launch(void* const* d_in, const int* in_sizes, int n_in,
                              void* d_out, int out_size, void* d_ws, size_t ws_size,
                              hipStream_t stream) {
    const float* x     = (const float*)d_in[0];
    const float* w1    = (const float*)d_in[1];
    const float* w2    = (const float*)d_in[2];
    const float* wsc   = (const float*)d_in[3];
    const float* sin   = (const float*)d_in[4];
    const float* srelu = (const float*)d_in[5];
    const float* sadd  = (const float*)d_in[6];
    const float* sw1   = (const float*)d_in[7];
    const float* sw2   = (const float*)d_in[8];
    const float* swsc  = (const float*)d_in[9];

    uint16_t* wbuf = (uint16_t*)d_ws;   // 32 KB bf16 weight matrix

    wprep_kernel<<<8, 256, 0, stream>>>(w2, wsc, sw2, swsc, wbuf);
    fused_kernel<<<NIMG * 112, 256, 0, stream>>>(x, w1, wbuf,
                                                 sin, srelu, sadd, sw1, sw2, swsc,
                                                 (float*)d_out);
}

// Round 14
// 116.568 us; speedup vs baseline: 1.1051x; 1.0184x over previous
//
#include <hip/hip_runtime.h>
#include <hip/hip_bf16.h>
#include <stdint.h>

#define NIMG 8
#define CIN  64
#define HWI  12544      // 112*112
#define COUT 128

typedef int v4i __attribute__((ext_vector_type(4)));

// fake-quant to int grid: round(x*inv) clamped to [lo,hi]
static __device__ __forceinline__ int q8(float x, float inv, float lo, float hi) {
    float t = rintf(x * inv);
    t = fminf(fmaxf(t, lo), hi);
    return (int)t;
}

// funnel shift: bytes of ({hi,lo} >> sh) — compiler emits v_alignbit_b32
static __device__ __forceinline__ uint32_t funnel(uint32_t hi, uint32_t lo, int sh) {
    return (uint32_t)(((((uint64_t)hi) << 32) | (uint64_t)lo) >> sh);
}

// signed-byte dot4: HW v_dot4_i32_i8 when available (1 inst vs ~16)
static __device__ __forceinline__ int dot4(uint32_t a, uint32_t b, int c) {
#if __has_builtin(__builtin_amdgcn_sdot4)
    return __builtin_amdgcn_sdot4((int)a, (int)b, c, false);
#else
    int acc = c;
    #pragma unroll
    for (int i = 0; i < 4; ++i)
        acc += (int)(int8_t)(a >> (8*i)) * (int)(int8_t)(b >> (8*i));
    return acc;
#endif
}

// ---------------------------------------------------------------------------
// K0: quantize 1x1 weights into int8 matrix [128 co][128 k] in ws
//     k<64: w2q ; k>=64: wscq.  offs[co] = 128 * sum_k w2q[co][k]
//     (compensation for biased yq-128 B operand).  16-lane shuffle reduce.
// ---------------------------------------------------------------------------
__global__ void __launch_bounds__(256) wprep_kernel(
    const float* __restrict__ w2, const float* __restrict__ wsc,
    const float* __restrict__ sw2p, const float* __restrict__ swscp,
    int8_t* __restrict__ wbuf, int* __restrict__ offs)
{
    int t = blockIdx.x * 256 + threadIdx.x;   // 2048 threads, 4+4 weights each
    int f = t * 4;
    int co = f >> 6, k = f & 63;              // 16 consecutive threads per co
    float inv2 = 1.0f / sw2p[0];
    float invs = 1.0f / swscp[0];
    float4 a = *(const float4*)(w2 + f);
    float4 b = *(const float4*)(wsc + f);
    float av[4] = {a.x, a.y, a.z, a.w};
    float bv[4] = {b.x, b.y, b.z, b.w};
    uint32_t pa = 0, pb = 0;
    int partial = 0;
    #pragma unroll
    for (int j = 0; j < 4; ++j) {
        int qa = q8(av[j], inv2, -128.f, 127.f);
        int qb = q8(bv[j], invs, -128.f, 127.f);
        partial += qa;
        pa |= (uint32_t)(qa & 255) << (8*j);
        pb |= (uint32_t)(qb & 255) << (8*j);
    }
    *(uint32_t*)(wbuf + co*128 + k)      = pa;
    *(uint32_t*)(wbuf + co*128 + 64 + k) = pb;
    // reduce partial over the 16 threads sharing co (same wave)
    partial += __shfl_xor(partial, 1, 16);
    partial += __shfl_xor(partial, 2, 16);
    partial += __shfl_xor(partial, 4, 16);
    partial += __shfl_xor(partial, 8, 16);
    if ((t & 15) == 0) offs[co] = partial << 7;
}

// ---------------------------------------------------------------------------
// K1 (fused, 1 row/block, 896 blocks):
//   ph0: hoisted loads — w1 taps, int8 A fragments, offs
//   ph1: x loads in 3 batches of 7 float4 -> quant -> tile
//   ph2: depthwise 3x3 (sdot4) + relu-quant -> Bl int8 [112 px][144]
//        (k 0..63 = yq-128 biased, 64..127 = xq)
//   ph3: mfma_i32_16x16x64_i8 — raw b128 B loads, NO unpack; requant; fp32 out
// LDS = 22272 + 16128 = 38400 B -> 4 blocks/CU; launch_bounds(256,4).
// i8-MFMA layout validated empirically: r3 (i8) == r4 (verified bf16) output.
// ---------------------------------------------------------------------------
__global__ void __launch_bounds__(256, 4) fused_kernel(
    const float* __restrict__ x, const float* __restrict__ w1,
    const int8_t* __restrict__ wbuf, const int* __restrict__ offs,
    const float* __restrict__ sinp, const float* __restrict__ srelup,
    const float* __restrict__ saddp, const float* __restrict__ sw1p,
    const float* __restrict__ sw2p, const float* __restrict__ swscp,
    float* __restrict__ out)
{
    __shared__ int8_t tile[64 * 348];   // c-stride 348 B (87 dwords, odd)
    __shared__ int8_t Bl[112 * 144];    // px-stride 144 B (16B-aligned for b128)

    int bid = blockIdx.x;
    int n = bid / 112, h = bid - n*112;
    int tid = threadIdx.x;
    int wave = tid >> 6, lane = tid & 63;
    int lr = lane >> 4, ln = lane & 15;
    float sin_f = sinp[0];
    float inv_sin = 1.0f / sin_f;

    // ---- phase 0a: depthwise taps for this thread's channel ----
    int c = lane;
    float isw1 = 1.0f / sw1p[0];
    uint32_t wp[3];
    #pragma unroll
    for (int ky = 0; ky < 3; ++ky) {
        uint32_t pk = 0;
        #pragma unroll
        for (int kx = 0; kx < 3; ++kx) {
            int q = q8(w1[c*9 + ky*3 + kx], isw1, -128.0f, 127.0f);
            pk |= (uint32_t)(q & 255) << (8*kx);
        }
        wp[ky] = pk;
    }

    // ---- phase 0b: int8 A fragments + offset rows (L2-resident) ----
    // a[mi][half]: m = (wave*2+mi)*16 + ln, k-bytes = half*64 + lr*16 .. +15
    v4i a[2][2];
    int4 ofr[2];
    #pragma unroll
    for (int mi = 0; mi < 2; ++mi) {
        int mt = wave*2 + mi;
        int m = mt*16 + ln;
        a[mi][0] = *(const v4i*)(wbuf + (size_t)m*128 + lr*16);
        a[mi][1] = *(const v4i*)(wbuf + (size_t)m*128 + 64 + lr*16);
        ofr[mi]  = *(const int4*)(offs + mt*16 + lr*4);
    }

    // ---- phase 1: 3 batches of 7 float4 (28 VGPRs in flight) ----
    #pragma unroll
    for (int b = 0; b < 3; ++b) {
        float4 vals[7];
        #pragma unroll
        for (int i = 0; i < 7; ++i) {
            int id = tid + (b*7 + i)*256;
            int cc = id / 84; int rem = id - cc*84;
            int r = rem / 28; int seg = rem - r*28;
            int grow = h + r - 1;
            vals[i] = make_float4(0.f, 0.f, 0.f, 0.f);
            if ((unsigned)grow < 112u)
                vals[i] = *(const float4*)(x + ((size_t)(n*64 + cc) * HWI + grow*112 + seg*4));
        }
        #pragma unroll
        for (int i = 0; i < 7; ++i) {
            int id = tid + (b*7 + i)*256;
            int cc = id / 84; int rem = id - cc*84;
            int r = rem / 28; int seg = rem - r*28;
            float vv[4] = {vals[i].x, vals[i].y, vals[i].z, vals[i].w};
            uint32_t pk = 0;
            #pragma unroll
            for (int e = 0; e < 4; ++e) {
                int q = q8(vv[e], inv_sin, -128.0f, 127.0f);
                pk |= (uint32_t)(q & 255) << (8*e);
            }
            *(uint32_t*)&tile[cc*348 + r*116 + seg*4] = pk;
        }
    }
    if (tid < 192) {  // zero pad cols 112..115 of each (c, r)
        int cc = tid / 3, r = tid - cc*3;
        *(uint32_t*)&tile[cc*348 + r*116 + 112] = 0;
    }
    __syncthreads();

    // ---- phase 2: depthwise 3x3 + relu-quant; int8 yq-128 / xq into Bl ----
    {
        int w0b = wave * 28;              // 28-px quarter of the row
        float r1 = (sin_f * sw1p[0]) / srelup[0];

        int base[3];
        #pragma unroll
        for (int r2 = 0; r2 < 3; ++r2) base[r2] = c*348 + r2*116;

        uint32_t Ar[3], Br[3], Cr[3];
        #pragma unroll
        for (int r2 = 0; r2 < 3; ++r2) {
            Ar[r2] = wave ? *(uint32_t*)&tile[base[r2] + w0b - 4] : 0u;
            Br[r2] = *(uint32_t*)&tile[base[r2] + w0b];
            Cr[r2] = *(uint32_t*)&tile[base[r2] + w0b + 4];
        }

        #pragma unroll
        for (int q = 0; q < 7; ++q) {
            int acc0 = 0, acc1 = 0, acc2 = 0, acc3 = 0;
            #pragma unroll
            for (int r2 = 0; r2 < 3; ++r2) {
                uint32_t d0 = funnel(Br[r2], Ar[r2], 24);
                uint32_t d1 = Br[r2];
                uint32_t d2 = funnel(Cr[r2], Br[r2], 8);
                uint32_t d3 = funnel(Cr[r2], Br[r2], 16);
                acc0 = dot4(d0, wp[r2], acc0);
                acc1 = dot4(d1, wp[r2], acc1);
                acc2 = dot4(d2, wp[r2], acc2);
                acc3 = dot4(d3, wp[r2], acc3);
            }
            int accs[4] = {acc0, acc1, acc2, acc3};
            uint32_t xdw = Br[1];
            int pxb = w0b + q*4;
            #pragma unroll
            for (int j = 0; j < 4; ++j) {
                float t = rintf((float)accs[j] * r1);
                t = fminf(fmaxf(t, 0.0f), 255.0f);
                Bl[(pxb + j)*144 + c]      = (int8_t)((int)t - 128);         // yq-128
                Bl[(pxb + j)*144 + 64 + c] = (int8_t)((xdw >> (8*j)) & 255); // xq
            }
            #pragma unroll
            for (int r2 = 0; r2 < 3; ++r2) { Ar[r2] = Br[r2]; Br[r2] = Cr[r2]; }
            if (q < 6) {
                #pragma unroll
                for (int r2 = 0; r2 < 3; ++r2)
                    Cr[r2] = *(uint32_t*)&tile[base[r2] + w0b + q*4 + 8];
            }
        }
    }
    __syncthreads();

    // ---- phase 3: GEMM (mfma_i32_16x16x64_i8) + requant epilogue ----
    {
        float S2  = sw2p[0] * srelup[0];
        float Ssc = swscp[0] * sinp[0];
        float sadd = saddp[0];
        float inv_sadd = 1.0f / sadd;

        size_t orow = (size_t)n*COUT*HWI + (size_t)h*112;

        for (int nt = 0; nt < 7; ++nt) {
            int px = nt*16 + ln;
            const int8_t* bp = &Bl[px*144 + lr*16];
            v4i b0 = *(const v4i*)bp;          // yq-128 bytes (k<64)
            v4i b1 = *(const v4i*)(bp + 64);   // xq bytes   (k>=64)
            #pragma unroll
            for (int mi = 0; mi < 2; ++mi) {
                v4i z = {0, 0, 0, 0};
                v4i c2 = __builtin_amdgcn_mfma_i32_16x16x64_i8(a[mi][0], b0, z, 0, 0, 0);
                v4i cs = __builtin_amdgcn_mfma_i32_16x16x64_i8(a[mi][1], b1, z, 0, 0, 0);
                int o4[4] = {ofr[mi].x, ofr[mi].y, ofr[mi].z, ofr[mi].w};
                size_t obase = orow + (size_t)((wave*2 + mi)*16 + lr*4)*HWI + px;
                #pragma unroll
                for (int r = 0; r < 4; ++r) {
                    float v = S2 * (float)(c2[r] + o4[r]) + Ssc * (float)cs[r];
                    float t = rintf(v * inv_sadd);
                    t = fminf(fmaxf(t, -128.0f), 127.0f);
                    out[obase + (size_t)r*HWI] = t * sadd;
                }
            }
        }
    }
}

// ---------------------------------------------------------------------------
extern "C" void kernel_launch(void* const* d_in, const int* in_sizes, int n_in,
                              void* d_out, int out_size, void* d_ws, size_t ws_size,
                              hipStream_t stream) {
    const float* x     = (const float*)d_in[0];
    const float* w1    = (const float*)d_in[1];
    const float* w2    = (const float*)d_in[2];
    const float* wsc   = (const float*)d_in[3];
    const float* sin   = (const float*)d_in[4];
    const float* srelu = (const float*)d_in[5];
    const float* sadd  = (const float*)d_in[6];
    const float* sw1   = (const float*)d_in[7];
    const float* sw2   = (const float*)d_in[8];
    const float* swsc  = (const float*)d_in[9];

    int8_t* wbuf = (int8_t*)d_ws;                      // 16 KB int8 weights
    int*    offs = (int*)(wbuf + (size_t)COUT * 128);  // 512 B

    wprep_kernel<<<8, 256, 0, stream>>>(w2, wsc, sw2, swsc, wbuf, offs);
    fused_kernel<<<NIMG * 112, 256, 0, stream>>>(x, w1, wbuf, offs,
                                                 sin, srelu, sadd, sw1, sw2, swsc,
                                                 (float*)d_out);
}